// Round 3
// baseline (281.381 us; speedup 1.0000x reference)
//
#include <hip/hip_runtime.h>

// IndexNSW: batched greedy best-first NSW search.
// One WAVE per query (B=64 blocks x 64 threads). A single wave is lockstep:
// no __syncthreads anywhere; DS ops from one wave complete in program order,
// shfl handles all cross-lane traffic.
// Lanes l and l^32 pair on neighbor (l&31): each covers 128 of the 256 dims
// (float4 qv[32] per lane -- the R2 bug was covering only 32 dims/lane).
// Merge uses a monotone 64-bit key (f32 bits of d, concat idx) so u64
// compare == (d, idx) lexicographic == lax.top_k stable order (d >= 0 always).

#define DIMS   256
#define RDEG   32
#define EFPOOL 32
#define KOUT   10
#define NWORDS 3125     // ceil(100000 / 32)
#define INF_D  1e30f

__global__ __launch_bounds__(64, 1) void nsw_wave_kernel(
    const float* __restrict__ query,    // [B, 256]
    const float* __restrict__ storage,  // [N, 256]
    const int*   __restrict__ graph,    // [N, 32]
    const int*   __restrict__ initial,  // [B, 32]
    float*       __restrict__ out,      // [B*10 ids as float][B*10 dists]
    int B)
{
    __shared__ unsigned int visited[NWORDS];
    __shared__ unsigned int expanded[NWORDS];
    __shared__ float sc_d[EFPOOL];      // merge scatter scratch
    __shared__ int   sc_id[EFPOOL];

    const int l    = threadIdx.x;   // 0..63
    const int b    = blockIdx.x;
    const int nb   = l & 31;        // neighbor / pool slot owned (duplicated across halves)
    const int half = l >> 5;        // which 128-dim half of the row this lane covers

    // zero bitmaps (single wave: no barrier needed before use)
    for (int i = l; i < NWORDS; i += 64) { visited[i] = 0u; expanded[i] = 0u; }

    // query half: dims [half*128, half*128+128) in registers = 32 float4
    float4 qv[32];
    {
        const float4* qp = reinterpret_cast<const float4*>(query + (size_t)b * DIMS) + half * 32;
        #pragma unroll
        for (int j = 0; j < 32; ++j) qv[j] = qp[j];
    }

    // half-distance: this lane's 128-dim partial sq-distance to row id
    auto halfdist = [&](int id) -> float {
        const float4* sp = reinterpret_cast<const float4*>(storage + (size_t)id * DIMS) + half * 32;
        float4 r[32];
        #pragma unroll
        for (int j = 0; j < 32; ++j) r[j] = sp[j];      // 32 outstanding loads
        float a0 = 0.f, a1 = 0.f, a2 = 0.f, a3 = 0.f;
        #pragma unroll
        for (int j = 0; j < 32; ++j) {
            float d0 = r[j].x - qv[j].x; a0 = fmaf(d0, d0, a0);
            float d1 = r[j].y - qv[j].y; a1 = fmaf(d1, d1, a1);
            float d2 = r[j].z - qv[j].z; a2 = fmaf(d2, d2, a2);
            float d3 = r[j].w - qv[j].w; a3 = fmaf(d3, d3, a3);
        }
        return (a0 + a1) + (a2 + a3);
    };

    // ---- initial pool: slot nb = (dist(init[nb]), init[nb]) ----
    int pool_id = initial[b * EFPOOL + nb];             // halves duplicate
    if (l < 32) atomicOr(&visited[pool_id >> 5], 1u << (pool_id & 31));
    float pool_d;
    {
        float part = halfdist(pool_id);
        pool_d = part + __shfl_xor(part, 32, 64);       // combine halves
    }

    // ---- ef_search expansion steps ----
    for (int step = 0; step < EFPOOL; ++step) {
        // 1) pick closest unexpanded candidate (argmin, tie -> lowest pool index)
        unsigned ew = expanded[pool_id >> 5];
        bool ex = (ew >> (pool_id & 31)) & 1u;
        float pd = ex ? INF_D : pool_d;
        int   ix = nb;
        #pragma unroll
        for (int m = 16; m >= 1; m >>= 1) {             // halves hold identical data
            float od = __shfl_xor(pd, m, 64);
            int   oi = __shfl_xor(ix, m, 64);
            if (od < pd || (od == pd && oi < ix)) { pd = od; ix = oi; }
        }
        int jx = __builtin_amdgcn_readfirstlane(ix);
        int u  = __shfl(pool_id, jx, 64);               // uniform jx -> readlane
        if (l == 0) atomicOr(&expanded[u >> 5], 1u << (u & 31));

        // 2) neighbors: gather row, fresh = !visited (read-all-then-write-all;
        //    in-wave DS ops are in program order, so the reads precede the ORs)
        int nbid = graph[(size_t)u * RDEG + nb];
        unsigned vw = visited[nbid >> 5];
        bool fresh = !((vw >> (nbid & 31)) & 1u);
        if (l < 32 && fresh) atomicOr(&visited[nbid >> 5], 1u << (nbid & 31));

        // 3) distances for fresh neighbors (lanes l, l^32 pair on neighbor nb;
        //    identical nbid/fresh in both halves -> shfl partner is active)
        float part = fresh ? halfdist(nbid) : 0.f;
        float nd = part + __shfl_xor(part, 32, 64);
        if (!fresh) nd = INF_D;

        // 4) stable top-32 merge == lax.top_k(-all_d, 32).
        //    Lane l holds concat element l: [0,32)=old pool, [32,64)=new cands.
        //    d >= 0 always => f32 bits monotone; key = (bits(d)<<6)|concat_idx
        //    gives u64 order == (d, idx) lexicographic (stable tie-break).
        float ed  = half ? nd   : pool_d;
        int   eid = half ? nbid : pool_id;
        unsigned long long key =
            ((unsigned long long)__float_as_uint(ed) << 6) | (unsigned)l;
        int rank = 0;
        #pragma unroll
        for (int j = 0; j < 64; ++j) {
            unsigned long long kj = __shfl(key, j, 64);
            rank += (kj < key) ? 1 : 0;
        }
        if (rank < EFPOOL) { sc_d[rank] = ed; sc_id[rank] = eid; }  // ranks unique
        pool_d  = sc_d[nb];                             // in-order DS: no barrier
        pool_id = sc_id[nb];
    }

    // ---- output: pool sorted ascending; ids as float (exact < 2^24), then dists ----
    if (l < KOUT) {
        out[b * KOUT + l]            = (float)pool_id;
        out[B * KOUT + b * KOUT + l] = pool_d;
    }
}

extern "C" void kernel_launch(void* const* d_in, const int* in_sizes, int n_in,
                              void* d_out, int out_size, void* d_ws, size_t ws_size,
                              hipStream_t stream) {
    const float* query   = (const float*)d_in[0];
    const float* storage = (const float*)d_in[1];
    const int*   graph   = (const int*)d_in[2];
    const int*   initial = (const int*)d_in[3];
    float* out = (float*)d_out;

    const int B = in_sizes[0] / DIMS;   // 64

    nsw_wave_kernel<<<B, 64, 0, stream>>>(query, storage, graph, initial, out, B);
}

// Round 4
// 235.044 us; speedup vs baseline: 1.1971x; 1.1971x over previous
//
#include <hip/hip_runtime.h>

// IndexNSW: batched greedy best-first NSW search. One WAVE per query
// (B=64 blocks x 64 threads), zero barriers (single-wave lockstep; DS ops
// are program-ordered within a wave).
//
// R4 changes vs R3 (151us):
//  - query row lives in LDS, not VGPRs -> all 32 storage float4 loads fit
//    in-flight (R3: 176 VGPRs => ~3 serialized load batches = 3 HBM trips)
//  - storage rows loaded UNconditionally (fresh only masks the distance) so
//    loads issue before the visited check instead of after it
//  - pool is kept top_k-sorted, so the reference argmin == first unexpanded
//    slot: ballot+ffs instead of a 6-deep dependent shfl_xor chain; the
//    initial (unsorted) pool is sorted by one merge pass vs an INF dummy
//    pool, which is semantics-preserving (stable (d, concat-idx) order)
//  - rank loop reads keys via LDS broadcast (64 ds_read_b64) instead of
//    128 shfl DS ops
// Merge key = (f32 bits of d)<<6 | concat idx: d>=0 so u64 order ==
// (d, idx) lexicographic == lax.top_k stable order, incl. duplicate-id ties.

#define DIMS   256
#define RDEG   32
#define EFPOOL 32
#define KOUT   10
#define NWORDS 3125     // ceil(100000 / 32)
#define INF_D  1e30f

__global__ __launch_bounds__(64, 1) void nsw_wave_kernel(
    const float* __restrict__ query,    // [B, 256]
    const float* __restrict__ storage,  // [N, 256]
    const int*   __restrict__ graph,    // [N, 32]
    const int*   __restrict__ initial,  // [B, 32]
    float*       __restrict__ out,      // [B*10 ids as float][B*10 dists]
    int B)
{
    __shared__ unsigned int visited[NWORDS];
    __shared__ unsigned int expanded[NWORDS];
    __shared__ float4 qsh[DIMS / 4];            // query row, 64 float4
    __shared__ unsigned long long keys[64];     // merge keys
    __shared__ float sc_d[EFPOOL];              // merge scatter scratch
    __shared__ int   sc_id[EFPOOL];

    const int l    = threadIdx.x;   // 0..63
    const int b    = blockIdx.x;
    const int nb   = l & 31;        // neighbor / pool slot owned (dup across halves)
    const int half = l >> 5;        // which 128-dim half this lane covers

    for (int i = l; i < NWORDS; i += 64) { visited[i] = 0u; expanded[i] = 0u; }

    // stage query row to LDS (coalesced: lane l -> float4 l)
    qsh[l] = reinterpret_cast<const float4*>(query + (size_t)b * DIMS)[l];

    float pool_d  = INF_D;   // dummy pool; first merge sorts the real entries in
    int   pool_id = 0;
    int   u;                 // current node to expand (set by merge_pick)

    // merge 64 concat elements (lane l owns concat idx l: [0,32)=old pool,
    // [32,64)=new cands) == lax.top_k(-all_d, 32), then pick next u =
    // first unexpanded slot of the sorted pool (== reference argmin).
    auto merge_pick = [&](float nd, int nbid) {
        float ed  = half ? nd   : pool_d;
        int   eid = half ? nbid : pool_id;
        unsigned long long key =
            ((unsigned long long)__float_as_uint(ed) << 6) | (unsigned)l;
        keys[l] = key;
        int rank = 0;
        #pragma unroll
        for (int j = 0; j < 64; ++j)            // same addr all lanes: broadcast
            rank += (keys[j] < key) ? 1 : 0;
        if (rank < EFPOOL) { sc_d[rank] = ed; sc_id[rank] = eid; }  // ranks unique
        pool_d  = sc_d[nb];                     // in-order DS: no barrier
        pool_id = sc_id[nb];
        // pick: first unexpanded slot in sorted order; all-expanded -> slot 0
        bool unexp = !((expanded[pool_id >> 5] >> (pool_id & 31)) & 1u);
        unsigned long long m = __ballot(unexp && (l < 32));
        int slot = (m == 0ull) ? 0 : (__ffsll((unsigned long long)m) - 1);
        u = sc_id[slot];                        // uniform slot: broadcast read
        if (l == 0) expanded[u >> 5] |= (1u << (u & 31));   // sole writer
    };

    // ---- initial pool: dists of init ids, sorted in via merge vs dummy INF pool ----
    {
        int nbid = initial[b * EFPOOL + nb];    // halves duplicate
        const float4* sp = reinterpret_cast<const float4*>(storage + (size_t)nbid * DIMS) + half * 32;
        float4 r[32];
        #pragma unroll
        for (int j = 0; j < 32; ++j) r[j] = sp[j];
        if (l < 32) atomicOr(&visited[nbid >> 5], 1u << (nbid & 31));
        float a0 = 0.f, a1 = 0.f, a2 = 0.f, a3 = 0.f;
        #pragma unroll
        for (int j = 0; j < 32; ++j) {
            float4 q = qsh[half * 32 + j];
            float d0 = r[j].x - q.x; a0 = fmaf(d0, d0, a0);
            float d1 = r[j].y - q.y; a1 = fmaf(d1, d1, a1);
            float d2 = r[j].z - q.z; a2 = fmaf(d2, d2, a2);
            float d3 = r[j].w - q.w; a3 = fmaf(d3, d3, a3);
        }
        float part = (a0 + a1) + (a2 + a3);
        float nd = part + __shfl_xor(part, 32, 64);
        merge_pick(nd, nbid);
    }

    // ---- ef_search expansion steps ----
    for (int step = 0; step < EFPOOL; ++step) {
        // neighbors of u; storage loads issue BEFORE the visited check
        int nbid = graph[(size_t)u * RDEG + nb];
        const float4* sp = reinterpret_cast<const float4*>(storage + (size_t)nbid * DIMS) + half * 32;
        float4 r[32];
        #pragma unroll
        for (int j = 0; j < 32; ++j) r[j] = sp[j];      // 32 loads in flight

        // fresh = !visited pre-update (read-all precedes OR: program order)
        unsigned vw = visited[nbid >> 5];
        bool fresh = !((vw >> (nbid & 31)) & 1u);
        if ((l < 32) && fresh) atomicOr(&visited[nbid >> 5], 1u << (nbid & 31));

        float a0 = 0.f, a1 = 0.f, a2 = 0.f, a3 = 0.f;
        #pragma unroll
        for (int j = 0; j < 32; ++j) {
            float4 q = qsh[half * 32 + j];
            float d0 = r[j].x - q.x; a0 = fmaf(d0, d0, a0);
            float d1 = r[j].y - q.y; a1 = fmaf(d1, d1, a1);
            float d2 = r[j].z - q.z; a2 = fmaf(d2, d2, a2);
            float d3 = r[j].w - q.w; a3 = fmaf(d3, d3, a3);
        }
        float part = (a0 + a1) + (a2 + a3);
        float d = part + __shfl_xor(part, 32, 64);      // halves have same nbid
        float nd = fresh ? d : INF_D;

        merge_pick(nd, nbid);
    }

    // ---- output: pool sorted ascending; ids as float (exact < 2^24), then dists ----
    if (l < KOUT) {
        out[b * KOUT + l]            = (float)pool_id;
        out[B * KOUT + b * KOUT + l] = pool_d;
    }
}

extern "C" void kernel_launch(void* const* d_in, const int* in_sizes, int n_in,
                              void* d_out, int out_size, void* d_ws, size_t ws_size,
                              hipStream_t stream) {
    const float* query   = (const float*)d_in[0];
    const float* storage = (const float*)d_in[1];
    const int*   graph   = (const int*)d_in[2];
    const int*   initial = (const int*)d_in[3];
    float* out = (float*)d_out;

    const int B = in_sizes[0] / DIMS;   // 64

    nsw_wave_kernel<<<B, 64, 0, stream>>>(query, storage, graph, initial, out, B);
}